// Round 1
// 449.195 us; speedup vs baseline: 1.2201x; 1.2201x over previous
//
#include <hip/hip_runtime.h>
#include <stdint.h>

#define EPS 1e-20f
#define H_ 192
#define W_ 192
#define HW_ 36864
#define CH4 128
#define OUTELEMS 18874368  // 4*128*36864 elements per output tensor

typedef __attribute__((ext_vector_type(8))) short bf16x8;
typedef __attribute__((ext_vector_type(4))) float f32x4;

// ---- bf16 pack helpers (RNE) for intermediates ----
__device__ __forceinline__ unsigned short f2bf(float f) {
  unsigned u = __float_as_uint(f);
  return (unsigned short)((u + 0x7fffu + ((u >> 16) & 1u)) >> 16);
}
__device__ __forceinline__ float bflo(unsigned v) { return __uint_as_float(v << 16); }
__device__ __forceinline__ float bfhi(unsigned v) { return __uint_as_float(v & 0xffff0000u); }

// ---- k0: pack channel_weight into MFMA A-fragments (hi/lo bf16 split) + sums ----
// AW layout: n = ((ot*4 + kb)*64 + lane)*8 + t
//   lane = r + 16*g  ->  A row (output) o = ot*16 + r ; k-elem ch = kb*32 + g*8 + t
__global__ void __launch_bounds__(256) k0_prep(const float* __restrict__ cw,
                                               const float* __restrict__ sw,
                                               unsigned short* __restrict__ AWhi,
                                               unsigned short* __restrict__ AWlo,
                                               float* __restrict__ sums) {
  int tid = threadIdx.x;
  if (blockIdx.x < 64) {
    int n = blockIdx.x * 256 + tid;   // 0..16383
    int t = n & 7;
    int l = (n >> 3) & 63;
    int kb = (n >> 9) & 3;
    int ot = n >> 11;
    int o = ot * 16 + (l & 15);
    int i = kb * 32 + (l >> 4) * 8 + t;
    float wv = cw[o * 128 + i];
    unsigned short hi = f2bf(wv);
    float hif = bflo((unsigned)hi);
    unsigned short lo = f2bf(wv - hif);
    AWhi[n] = hi;
    AWlo[n] = lo;
  } else {
    __shared__ float red[256];
    float s = 0.f;
    for (int k = tid; k < 16384; k += 256) s += cw[k];
    red[tid] = s; __syncthreads();
    for (int off = 128; off > 0; off >>= 1) {
      if (tid < off) red[tid] += red[tid + off];
      __syncthreads();
    }
    if (tid == 0) sums[0] = red[0];
    __syncthreads();
    s = 0.f;
    for (int k = tid; k < 3200; k += 256) s += sw[k];
    red[tid] = s; __syncthreads();
    for (int off = 128; off > 0; off >>= 1) {
      if (tid < off) red[tid] += red[tid + off];
      __syncthreads();
    }
    if (tid == 0) sums[1] = red[0];
  }
}

// ---- k1: stencil stage -> packed (X=ce1*e1, Y=ce1) bf16x2, planar (B,128,H,W) ----
__global__ void __launch_bounds__(256) k1_stage1(
    const float* __restrict__ d, const float* __restrict__ cd,
    const float* __restrict__ e, const float* __restrict__ ce,
    const float* __restrict__ wprop, const float* __restrict__ wsd,
    unsigned* __restrict__ XY) {
  const int tid = threadIdx.x;
  const int tile = blockIdx.x;  // 36 tiles of 32x32
  const int th0 = (tile / 6) * 32, tw0 = (tile % 6) * 32;
  const int bc = blockIdx.y;  // b*32+c
  const int b = bc >> 5, c = bc & 31;

  __shared__ float dpL[1296], cdpL[1296];
  __shared__ float dmnL[1156], dmxL[1156], cmnL[1156], cmxL[1156];

  const float* dB = d + bc * HW_;
  const float* cdB = cd + bc * HW_;
  for (int idx = tid; idx < 1296; idx += 256) {
    int ly = idx / 36, lx = idx % 36;
    int gy = th0 + ly - 2, gx = tw0 + lx - 2;
    float dv = 0.f, cv = 0.f;
    if (gy >= 0 && gy < H_ && gx >= 0 && gx < W_) {
      dv = dB[gy * W_ + gx];
      cv = cdB[gy * W_ + gx];
    }
    dpL[idx] = dv; cdpL[idx] = cv;
  }
  __syncthreads();

  for (int idx = tid; idx < 1156; idx += 256) {
    int ly = idx / 34, lx = idx % 34;
    float bkx = -1.f, bkn = -1.f;
    float dmx = 0.f, cmx = 0.f, dmn = 0.f, cmn = 0.f;
#pragma unroll
    for (int di = 0; di < 3; ++di) {
#pragma unroll
      for (int dj = 0; dj < 3; ++dj) {
        int gpy = th0 + ly + di - 1, gpx = tw0 + lx + dj - 1;
        float dv = dpL[(ly + di) * 36 + lx + dj];
        float cv = cdpL[(ly + di) * 36 + lx + dj];
        bool inb = (gpy >= 0) & (gpy < H_ + 2) & (gpx >= 0) & (gpx < W_ + 2);
        float kx = inb ? dv * cv : -1.f;
        float kn = inb ? cv / (dv + EPS) : -1.f;
        if (kx > bkx) { bkx = kx; dmx = dv; cmx = cv; }
        if (kn > bkn) { bkn = kn; dmn = dv; cmn = cv; }
      }
    }
    dmxL[idx] = dmx; cmxL[idx] = cmx; dmnL[idx] = dmn; cmnL[idx] = cmn;
  }
  __syncthreads();

  const float wp = wprop[c];
  float wq[8];
#pragma unroll
  for (int t = 0; t < 8; ++t) wq[t] = wsd[c * 8 + t];

  const int offy[4] = {-1, -1, -1, 0};
  const int offx[4] = {-1, 0, 1, 1};

  for (int idx = tid; idx < 1024; idx += 256) {
    int ly = idx >> 5, lx = idx & 31;
    int hh = th0 + ly, ww = tw0 + lx;
#pragma unroll
    for (int p = 0; p < 4; ++p) {
      int n1 = (ly + offy[p] + 1) * 34 + (lx + offx[p] + 1);
      int n2 = (ly - offy[p] + 1) * 34 + (lx - offx[p] + 1);
      float r0 = dmnL[n1] / (dmxL[n2] + EPS);
      float r1 = dmxL[n1] / (dmnL[n2] + EPS);
      float cr0 = cmnL[n1] * cmxL[n2];
      float cr1 = cmxL[n1] * cmnL[n2];
      float x0 = fminf(fmaxf(r0, EPS), 1.0f);
      float x1 = fminf(fmaxf(r1, EPS), 1.0f);
      float dr0 = exp2f(wq[p] * log2f(x0));
      float dr1 = exp2f(wq[4 + p] * log2f(x1));
      float ef, cf;
      if (cr1 * dr0 > cr0 * dr1) { ef = dr1; cf = cr1; } else { ef = dr0; cf = cr0; }
      int ei = (bc * 4 + p) * HW_ + hh * W_ + ww;
      float ev = e[ei], cev = ce[ei];
      float dn = wp * cev + cf;
      float e1 = (wp * cev * ev + cf * ef) / (dn + EPS);
      float ce1 = dn / (wp + 1.0f);
      XY[(b * CH4 + c * 4 + p) * HW_ + hh * W_ + ww] =
          (unsigned)f2bf(ce1 * e1) | ((unsigned)f2bf(ce1) << 16);
    }
  }
}

// ---- k2: per-pixel channel mix as bf16 MFMA GEMM pair ----
// Block: 256 thr = 4 waves; tile = 64 pixels x 128 outputs; K = 128 channels.
// LDS stage [128 ch][stride 66 u32] of packed XY; each wave owns 16 pixels.
__global__ void __launch_bounds__(256) k2_mix(const unsigned* __restrict__ XY,
                                              const unsigned short* __restrict__ AWhi,
                                              const unsigned short* __restrict__ AWlo,
                                              const float* __restrict__ sums,
                                              unsigned* __restrict__ PQ) {
  __shared__ unsigned L[128 * 66];  // stride 66: 2-way bank alias on frag reads (free)
  const int tid = threadIdx.x;
  const int blk = blockIdx.x;           // 2304 blocks
  const int b = blk / 576;
  const int hw0 = (blk % 576) * 64;
  const unsigned* xp = XY + (size_t)(b * CH4) * HW_ + hw0;

  // stage: 128 ch x 64 px u32, dwordx4 global loads, b64 LDS writes (8B aligned)
#pragma unroll
  for (int j = 0; j < 8; ++j) {
    int v = j * 256 + tid;      // 0..2047 vec4-index
    int ch = v >> 4;            // 16 vec4 per channel row
    int po = (v & 15) * 4;
    uint4 val = *reinterpret_cast<const uint4*>(xp + (size_t)ch * HW_ + po);
    unsigned* dst = &L[ch * 66 + po];
    *reinterpret_cast<uint2*>(dst) = make_uint2(val.x, val.y);
    *reinterpret_cast<uint2*>(dst + 2) = make_uint2(val.z, val.w);
  }
  __syncthreads();

  const int lane = tid & 63;
  const int w = tid >> 6;       // wave id -> pixel quarter
  const int c = lane & 15;      // MFMA N-col = pixel
  const int g = lane >> 4;      // k-group
  const int pbase = w * 16 + c;

  // B fragments: x (nom) and y (den), 4 K-blocks of 32
  bf16x8 xf[4], yf[4];
#pragma unroll
  for (int kb = 0; kb < 4; ++kb) {
    unsigned vv[8];
    const unsigned* base = &L[(kb * 32 + g * 8) * 66 + pbase];
#pragma unroll
    for (int t = 0; t < 8; ++t) vv[t] = base[t * 66];
    union { bf16x8 v; unsigned u[4]; } ux, uy;
#pragma unroll
    for (int p = 0; p < 4; ++p) {
      ux.u[p] = (vv[2 * p] & 0xffffu) | (vv[2 * p + 1] << 16);
      uy.u[p] = (vv[2 * p] >> 16) | (vv[2 * p + 1] & 0xffff0000u);
    }
    xf[kb] = ux.v;
    yf[kb] = uy.v;
  }

  const float inv = 1.0f / (sums[0] + EPS);
  unsigned* qp = PQ + (size_t)(b * CH4) * HW_ + hw0;

#pragma unroll 2
  for (int ot = 0; ot < 8; ++ot) {
    f32x4 accn = {0.f, 0.f, 0.f, 0.f};
    f32x4 accd = {0.f, 0.f, 0.f, 0.f};
#pragma unroll
    for (int kb = 0; kb < 4; ++kb) {
      int an = ((ot * 4 + kb) * 64 + lane) * 8;
      bf16x8 ahi = *reinterpret_cast<const bf16x8*>(AWhi + an);
      bf16x8 alo = *reinterpret_cast<const bf16x8*>(AWlo + an);
      accn = __builtin_amdgcn_mfma_f32_16x16x32_bf16(ahi, xf[kb], accn, 0, 0, 0);
      accn = __builtin_amdgcn_mfma_f32_16x16x32_bf16(alo, xf[kb], accn, 0, 0, 0);
      accd = __builtin_amdgcn_mfma_f32_16x16x32_bf16(ahi, yf[kb], accd, 0, 0, 0);
      accd = __builtin_amdgcn_mfma_f32_16x16x32_bf16(alo, yf[kb], accd, 0, 0, 0);
    }
    // C/D: col = lane&15 (pixel), row = g*4 + j (output within o-tile) [m89-verified]
#pragma unroll
    for (int j = 0; j < 4; ++j) {
      int o = ot * 16 + g * 4 + j;
      qp[(size_t)o * HW_ + w * 16 + c] =
          (unsigned)f2bf(accn[j] * inv) | ((unsigned)f2bf(accd[j] * inv) << 16);
    }
  }
}

// ---- k3: depthwise 5x5 conv on P,Q + final ratios -> FP32 outputs ----
__global__ void __launch_bounds__(256) k3_conv(const unsigned* __restrict__ PQ,
                                               const float* __restrict__ sw,
                                               const float* __restrict__ sums,
                                               float* __restrict__ out0,
                                               float* __restrict__ out1) {
  int t = blockIdx.x;
  int tile = t % 36;
  int chb = t / 36;  // b*128+ch
  int ch = chb & 127;
  int th0 = (tile / 6) * 32, tw0 = (tile % 6) * 32;
  __shared__ float Pt[1296], Qt[1296];
  const unsigned* src = PQ + chb * HW_;
  int tid = threadIdx.x;
  for (int idx = tid; idx < 1296; idx += 256) {
    int ly = idx / 36, lx = idx % 36;
    int gy = th0 + ly - 2, gx = tw0 + lx - 2;
    unsigned v = 0;
    if (gy >= 0 && gy < H_ && gx >= 0 && gx < W_) v = src[gy * W_ + gx];
    Pt[idx] = bflo(v); Qt[idx] = bfhi(v);
  }
  __syncthreads();
  float wr[25];
#pragma unroll
  for (int k = 0; k < 25; ++k) wr[k] = sw[ch * 25 + k];
  float isw = 1.0f / (sums[1] + EPS);
  int x = tid & 31, yg = tid >> 5;  // 32 cols x 8 row-groups (4 rows each)
  float an[4] = {0, 0, 0, 0}, ad[4] = {0, 0, 0, 0};
#pragma unroll
  for (int rr = 0; rr < 8; ++rr) {
    int Lr = yg * 4 + rr;
    float pv[5], qv[5];
#pragma unroll
    for (int c5 = 0; c5 < 5; ++c5) {
      pv[c5] = Pt[Lr * 36 + x + c5];
      qv[c5] = Qt[Lr * 36 + x + c5];
    }
#pragma unroll
    for (int k = 0; k < 4; ++k) {
      int ky = rr - k;
      if (ky >= 0 && ky <= 4) {
#pragma unroll
        for (int c5 = 0; c5 < 5; ++c5) {
          an[k] += pv[c5] * wr[ky * 5 + c5];
          ad[k] += qv[c5] * wr[ky * 5 + c5];
        }
      }
    }
  }
#pragma unroll
  for (int k = 0; k < 4; ++k) {
    int hh = th0 + yg * 4 + k;
    int oi = chb * HW_ + hh * W_ + tw0 + x;
    out0[oi] = an[k] / (ad[k] + EPS);
    out1[oi] = ad[k] * isw;
  }
}

extern "C" void kernel_launch(void* const* d_in, const int* in_sizes, int n_in,
                              void* d_out, int out_size, void* d_ws, size_t ws_size,
                              hipStream_t stream) {
  const float* d = (const float*)d_in[0];
  const float* cd = (const float*)d_in[1];
  const float* e = (const float*)d_in[2];
  const float* ce = (const float*)d_in[3];
  const float* wprop = (const float*)d_in[4];
  const float* wsd = (const float*)d_in[5];
  const float* cw = (const float*)d_in[6];
  const float* sw = (const float*)d_in[7];

  // ws layout (75.6 MB): sums(64 f32) | AWhi(16384 bf16) | AWlo(16384 bf16) | PQ(18874368 u32)
  // (AWhi+AWlo = 65536 B = the old 16384-f32 cwT region; PQ offset unchanged)
  // XY (bf16x2, 75.5 MB) staged in UPPER HALF of d_out; k2 consumes it before k3 writes.
  float* wsf = (float*)d_ws;
  float* sums = wsf;
  unsigned short* AWhi = (unsigned short*)(wsf + 64);
  unsigned short* AWlo = AWhi + 16384;
  unsigned* PQ = (unsigned*)(wsf + 64 + 16384);
  float* out0 = (float*)d_out;
  float* out1 = out0 + OUTELEMS;
  unsigned* XY = (unsigned*)(out0 + OUTELEMS);

  hipLaunchKernelGGL(k0_prep, dim3(65), dim3(256), 0, stream, cw, sw, AWhi, AWlo, sums);
  hipLaunchKernelGGL(k1_stage1, dim3(36, 128), dim3(256), 0, stream, d, cd, e, ce,
                     wprop, wsd, XY);
  hipLaunchKernelGGL(k2_mix, dim3(2304), dim3(256), 0, stream, XY, AWhi, AWlo, sums, PQ);
  hipLaunchKernelGGL(k3_conv, dim3(18432), dim3(256), 0, stream, PQ, sw, sums, out0,
                     out1);
}

// Round 2
// 417.129 us; speedup vs baseline: 1.3139x; 1.0769x over previous
//
#include <hip/hip_runtime.h>
#include <stdint.h>

#define EPS 1e-20f
#define H_ 192
#define W_ 192
#define HW_ 36864
#define CH4 128
#define OUTELEMS 18874368  // 4*128*36864 elements per output tensor

typedef __attribute__((ext_vector_type(8))) short bf16x8;
typedef __attribute__((ext_vector_type(4))) float f32x4;

// ---- bf16 pack helpers (RNE) for intermediates ----
__device__ __forceinline__ unsigned short f2bf(float f) {
  unsigned u = __float_as_uint(f);
  return (unsigned short)((u + 0x7fffu + ((u >> 16) & 1u)) >> 16);
}
__device__ __forceinline__ float bflo(unsigned v) { return __uint_as_float(v << 16); }
__device__ __forceinline__ float bfhi(unsigned v) { return __uint_as_float(v & 0xffff0000u); }

// ---- k0: pack channel_weight into MFMA A-fragments (hi/lo bf16 split) + sums ----
// AW layout: n = ((ot*4 + kb)*64 + lane)*8 + t
//   lane = r + 16*g  ->  A row (output) o = ot*16 + r ; k-elem ch = kb*32 + g*8 + t
__global__ void __launch_bounds__(256) k0_prep(const float* __restrict__ cw,
                                               const float* __restrict__ sw,
                                               unsigned short* __restrict__ AWhi,
                                               unsigned short* __restrict__ AWlo,
                                               float* __restrict__ sums) {
  int tid = threadIdx.x;
  if (blockIdx.x < 64) {
    int n = blockIdx.x * 256 + tid;   // 0..16383
    int t = n & 7;
    int l = (n >> 3) & 63;
    int kb = (n >> 9) & 3;
    int ot = n >> 11;
    int o = ot * 16 + (l & 15);
    int i = kb * 32 + (l >> 4) * 8 + t;
    float wv = cw[o * 128 + i];
    unsigned short hi = f2bf(wv);
    float hif = bflo((unsigned)hi);
    unsigned short lo = f2bf(wv - hif);
    AWhi[n] = hi;
    AWlo[n] = lo;
  } else {
    __shared__ float red[256];
    float s = 0.f;
    for (int k = tid; k < 16384; k += 256) s += cw[k];
    red[tid] = s; __syncthreads();
    for (int off = 128; off > 0; off >>= 1) {
      if (tid < off) red[tid] += red[tid + off];
      __syncthreads();
    }
    if (tid == 0) sums[0] = red[0];
    __syncthreads();
    s = 0.f;
    for (int k = tid; k < 3200; k += 256) s += sw[k];
    red[tid] = s; __syncthreads();
    for (int off = 128; off > 0; off >>= 1) {
      if (tid < off) red[tid] += red[tid + off];
      __syncthreads();
    }
    if (tid == 0) sums[1] = red[0];
  }
}

// ---- k1: stencil stage -> packed (X=ce1*e1, Y=ce1) bf16x2, planar (B,128,H,W) ----
// v2: keys computed ONCE per staged position (IEEE div kept for exact argmax),
//     argmax stored as packed u16 LDS offsets, fast rcp/log2/exp2 on the
//     continuous path (error ~1ulp << bf16 quantization of XY).
__global__ void __launch_bounds__(256) k1_stage1(
    const float* __restrict__ d, const float* __restrict__ cd,
    const float* __restrict__ e, const float* __restrict__ ce,
    const float* __restrict__ wprop, const float* __restrict__ wsd,
    unsigned* __restrict__ XY) {
  const int tid = threadIdx.x;
  const int tile = blockIdx.x;  // 36 tiles of 32x32
  const int th0 = (tile / 6) * 32, tw0 = (tile % 6) * 32;
  const int bc = blockIdx.y;  // b*32+c
  const int b = bc >> 5, c = bc & 31;

  // staged values + cached argmax keys at rows th0-2..th0+33 (36x36)
  __shared__ float dpL[1296], cdpL[1296], kxL[1296], knL[1296];
  // packed best-offset (low16 = j_max offset, high16 = j_min offset) on 34x34 grid
  __shared__ unsigned jxn[1156];

  const float* dB = d + bc * HW_;
  const float* cdB = cd + bc * HW_;
  for (int idx = tid; idx < 1296; idx += 256) {
    int ly = idx / 36, lx = idx % 36;
    int gy = th0 + ly - 2, gx = tw0 + lx - 2;  // original-image coords
    float dv = 0.f, cv = 0.f;
    if (gy >= 0 && gy < H_ && gx >= 0 && gx < W_) {
      dv = dB[gy * W_ + gx];
      cv = cdB[gy * W_ + gx];
    }
    dpL[idx] = dv; cdpL[idx] = cv;
    // key in-bounds iff inside the reference's zero-PADDED grid
    bool inb = (gy >= -1) & (gy <= H_) & (gx >= -1) & (gx <= W_);
    kxL[idx] = inb ? dv * cv : -1.f;          // -1 sentinel (< all real keys >= 0)
    knL[idx] = inb ? cv / (dv + EPS) : -1.f;  // IEEE div: exact argmax vs reference
  }
  __syncthreads();

  for (int idx = tid; idx < 1156; idx += 256) {
    int ly = idx / 34, lx = idx % 34;
    int base = ly * 36 + lx;
    float bkx = -1.f, bkn = -1.f;
    int ox = base + 37, on = base + 37;  // center (always in-grid)
#pragma unroll
    for (int di = 0; di < 3; ++di) {
#pragma unroll
      for (int dj = 0; dj < 3; ++dj) {
        int o = base + di * 36 + dj;
        float kx = kxL[o], kn = knL[o];
        if (kx > bkx) { bkx = kx; ox = o; }  // strict > = numpy argmax first-wins
        if (kn > bkn) { bkn = kn; on = o; }
      }
    }
    jxn[idx] = (unsigned)ox | ((unsigned)on << 16);
  }
  __syncthreads();

  const float wp = wprop[c];
  const float iwp1 = __builtin_amdgcn_rcpf(wp + 1.0f);
  float wq[8];
#pragma unroll
  for (int t = 0; t < 8; ++t) wq[t] = wsd[c * 8 + t];  // [ord*4 + pair]

  const int offy[4] = {-1, -1, -1, 0};
  const int offx[4] = {-1, 0, 1, 1};

  for (int idx = tid; idx < 1024; idx += 256) {
    int ly = idx >> 5, lx = idx & 31;
    int hh = th0 + ly, ww = tw0 + lx;
#pragma unroll
    for (int p = 0; p < 4; ++p) {
      int n1 = (ly + offy[p] + 1) * 34 + (lx + offx[p] + 1);
      int n2 = (ly - offy[p] + 1) * 34 + (lx - offx[p] + 1);
      unsigned u1 = jxn[n1], u2 = jxn[n2];
      int x1i = u1 & 0xffffu, m1i = u1 >> 16;
      int x2i = u2 & 0xffffu, m2i = u2 >> 16;
      float dmn1 = dpL[m1i], cmn1 = cdpL[m1i];
      float dmx1 = dpL[x1i], cmx1 = cdpL[x1i];
      float dmn2 = dpL[m2i], cmn2 = cdpL[m2i];
      float dmx2 = dpL[x2i], cmx2 = cdpL[x2i];
      // continuous path: fast rcp / native log2+exp2 (error ~1ulp << bf16 quantum)
      float r0 = dmn1 * __builtin_amdgcn_rcpf(dmx2 + EPS);
      float r1 = dmx1 * __builtin_amdgcn_rcpf(dmn2 + EPS);
      float cr0 = cmn1 * cmx2;
      float cr1 = cmx1 * cmn2;
      float x0 = fminf(fmaxf(r0, EPS), 1.0f);
      float x1 = fminf(fmaxf(r1, EPS), 1.0f);
      float dr0 = __builtin_amdgcn_exp2f(wq[p] * __builtin_amdgcn_logf(x0));
      float dr1 = __builtin_amdgcn_exp2f(wq[4 + p] * __builtin_amdgcn_logf(x1));
      // select ord with larger cr/dr; cross-multiplied (all >=0), tie -> ord0.
      float ef, cf;
      if (cr1 * dr0 > cr0 * dr1) { ef = dr1; cf = cr1; } else { ef = dr0; cf = cr0; }
      int ei = (bc * 4 + p) * HW_ + hh * W_ + ww;
      float ev = e[ei], cev = ce[ei];
      float dn = wp * cev + cf;
      float e1 = (wp * cev * ev + cf * ef) * __builtin_amdgcn_rcpf(dn + EPS);
      float ce1 = dn * iwp1;
      XY[(b * CH4 + c * 4 + p) * HW_ + hh * W_ + ww] =
          (unsigned)f2bf(ce1 * e1) | ((unsigned)f2bf(ce1) << 16);
    }
  }
}

// ---- k2: per-pixel channel mix as bf16 MFMA GEMM pair ----
// Block: 256 thr = 4 waves; tile = 64 pixels x 128 outputs; K = 128 channels.
// LDS stage [128 ch][stride 66 u32] of packed XY; each wave owns 16 pixels.
__global__ void __launch_bounds__(256) k2_mix(const unsigned* __restrict__ XY,
                                              const unsigned short* __restrict__ AWhi,
                                              const unsigned short* __restrict__ AWlo,
                                              const float* __restrict__ sums,
                                              unsigned* __restrict__ PQ) {
  __shared__ unsigned L[128 * 66];  // stride 66: 2-way bank alias on frag reads (free)
  const int tid = threadIdx.x;
  const int blk = blockIdx.x;           // 2304 blocks
  const int b = blk / 576;
  const int hw0 = (blk % 576) * 64;
  const unsigned* xp = XY + (size_t)(b * CH4) * HW_ + hw0;

  // stage: 128 ch x 64 px u32, dwordx4 global loads, b64 LDS writes (8B aligned)
#pragma unroll
  for (int j = 0; j < 8; ++j) {
    int v = j * 256 + tid;      // 0..2047 vec4-index
    int ch = v >> 4;            // 16 vec4 per channel row
    int po = (v & 15) * 4;
    uint4 val = *reinterpret_cast<const uint4*>(xp + (size_t)ch * HW_ + po);
    unsigned* dst = &L[ch * 66 + po];
    *reinterpret_cast<uint2*>(dst) = make_uint2(val.x, val.y);
    *reinterpret_cast<uint2*>(dst + 2) = make_uint2(val.z, val.w);
  }
  __syncthreads();

  const int lane = tid & 63;
  const int w = tid >> 6;       // wave id -> pixel quarter
  const int c = lane & 15;      // MFMA N-col = pixel
  const int g = lane >> 4;      // k-group
  const int pbase = w * 16 + c;

  // B fragments: x (nom) and y (den), 4 K-blocks of 32
  bf16x8 xf[4], yf[4];
#pragma unroll
  for (int kb = 0; kb < 4; ++kb) {
    unsigned vv[8];
    const unsigned* base = &L[(kb * 32 + g * 8) * 66 + pbase];
#pragma unroll
    for (int t = 0; t < 8; ++t) vv[t] = base[t * 66];
    union { bf16x8 v; unsigned u[4]; } ux, uy;
#pragma unroll
    for (int p = 0; p < 4; ++p) {
      ux.u[p] = (vv[2 * p] & 0xffffu) | (vv[2 * p + 1] << 16);
      uy.u[p] = (vv[2 * p] >> 16) | (vv[2 * p + 1] & 0xffff0000u);
    }
    xf[kb] = ux.v;
    yf[kb] = uy.v;
  }

  const float inv = 1.0f / (sums[0] + EPS);
  unsigned* qp = PQ + (size_t)(b * CH4) * HW_ + hw0;

#pragma unroll 2
  for (int ot = 0; ot < 8; ++ot) {
    f32x4 accn = {0.f, 0.f, 0.f, 0.f};
    f32x4 accd = {0.f, 0.f, 0.f, 0.f};
#pragma unroll
    for (int kb = 0; kb < 4; ++kb) {
      int an = ((ot * 4 + kb) * 64 + lane) * 8;
      bf16x8 ahi = *reinterpret_cast<const bf16x8*>(AWhi + an);
      bf16x8 alo = *reinterpret_cast<const bf16x8*>(AWlo + an);
      accn = __builtin_amdgcn_mfma_f32_16x16x32_bf16(ahi, xf[kb], accn, 0, 0, 0);
      accn = __builtin_amdgcn_mfma_f32_16x16x32_bf16(alo, xf[kb], accn, 0, 0, 0);
      accd = __builtin_amdgcn_mfma_f32_16x16x32_bf16(ahi, yf[kb], accd, 0, 0, 0);
      accd = __builtin_amdgcn_mfma_f32_16x16x32_bf16(alo, yf[kb], accd, 0, 0, 0);
    }
    // C/D: col = lane&15 (pixel), row = g*4 + j (output within o-tile) [m89-verified]
#pragma unroll
    for (int j = 0; j < 4; ++j) {
      int o = ot * 16 + g * 4 + j;
      qp[(size_t)o * HW_ + w * 16 + c] =
          (unsigned)f2bf(accn[j] * inv) | ((unsigned)f2bf(accd[j] * inv) << 16);
    }
  }
}

// ---- k3: depthwise 5x5 conv on P,Q + final ratios -> FP32 outputs ----
__global__ void __launch_bounds__(256) k3_conv(const unsigned* __restrict__ PQ,
                                               const float* __restrict__ sw,
                                               const float* __restrict__ sums,
                                               float* __restrict__ out0,
                                               float* __restrict__ out1) {
  int t = blockIdx.x;
  int tile = t % 36;
  int chb = t / 36;  // b*128+ch
  int ch = chb & 127;
  int th0 = (tile / 6) * 32, tw0 = (tile % 6) * 32;
  __shared__ float Pt[1296], Qt[1296];
  const unsigned* src = PQ + chb * HW_;
  int tid = threadIdx.x;
  for (int idx = tid; idx < 1296; idx += 256) {
    int ly = idx / 36, lx = idx % 36;
    int gy = th0 + ly - 2, gx = tw0 + lx - 2;
    unsigned v = 0;
    if (gy >= 0 && gy < H_ && gx >= 0 && gx < W_) v = src[gy * W_ + gx];
    Pt[idx] = bflo(v); Qt[idx] = bfhi(v);
  }
  __syncthreads();
  float wr[25];
#pragma unroll
  for (int k = 0; k < 25; ++k) wr[k] = sw[ch * 25 + k];
  float isw = 1.0f / (sums[1] + EPS);
  int x = tid & 31, yg = tid >> 5;  // 32 cols x 8 row-groups (4 rows each)
  float an[4] = {0, 0, 0, 0}, ad[4] = {0, 0, 0, 0};
#pragma unroll
  for (int rr = 0; rr < 8; ++rr) {
    int Lr = yg * 4 + rr;
    float pv[5], qv[5];
#pragma unroll
    for (int c5 = 0; c5 < 5; ++c5) {
      pv[c5] = Pt[Lr * 36 + x + c5];
      qv[c5] = Qt[Lr * 36 + x + c5];
    }
#pragma unroll
    for (int k = 0; k < 4; ++k) {
      int ky = rr - k;
      if (ky >= 0 && ky <= 4) {
#pragma unroll
        for (int c5 = 0; c5 < 5; ++c5) {
          an[k] += pv[c5] * wr[ky * 5 + c5];
          ad[k] += qv[c5] * wr[ky * 5 + c5];
        }
      }
    }
  }
#pragma unroll
  for (int k = 0; k < 4; ++k) {
    int hh = th0 + yg * 4 + k;
    int oi = chb * HW_ + hh * W_ + tw0 + x;
    out0[oi] = an[k] / (ad[k] + EPS);
    out1[oi] = ad[k] * isw;
  }
}

extern "C" void kernel_launch(void* const* d_in, const int* in_sizes, int n_in,
                              void* d_out, int out_size, void* d_ws, size_t ws_size,
                              hipStream_t stream) {
  const float* d = (const float*)d_in[0];
  const float* cd = (const float*)d_in[1];
  const float* e = (const float*)d_in[2];
  const float* ce = (const float*)d_in[3];
  const float* wprop = (const float*)d_in[4];
  const float* wsd = (const float*)d_in[5];
  const float* cw = (const float*)d_in[6];
  const float* sw = (const float*)d_in[7];

  // ws layout (75.6 MB): sums(64 f32) | AWhi(16384 bf16) | AWlo(16384 bf16) | PQ(18874368 u32)
  // XY (bf16x2, 75.5 MB) staged in UPPER HALF of d_out; k2 consumes it before k3 writes.
  float* wsf = (float*)d_ws;
  float* sums = wsf;
  unsigned short* AWhi = (unsigned short*)(wsf + 64);
  unsigned short* AWlo = AWhi + 16384;
  unsigned* PQ = (unsigned*)(wsf + 64 + 16384);
  float* out0 = (float*)d_out;
  float* out1 = out0 + OUTELEMS;
  unsigned* XY = (unsigned*)(out0 + OUTELEMS);

  hipLaunchKernelGGL(k0_prep, dim3(65), dim3(256), 0, stream, cw, sw, AWhi, AWlo, sums);
  hipLaunchKernelGGL(k1_stage1, dim3(36, 128), dim3(256), 0, stream, d, cd, e, ce,
                     wprop, wsd, XY);
  hipLaunchKernelGGL(k2_mix, dim3(2304), dim3(256), 0, stream, XY, AWhi, AWlo, sums, PQ);
  hipLaunchKernelGGL(k3_conv, dim3(18432), dim3(256), 0, stream, PQ, sw, sums, out0,
                     out1);
}